// Round 12
// baseline (92.651 us; speedup 1.0000x reference)
//
#include <hip/hip_runtime.h>
#include <hip/hip_bf16.h>
#include <cfloat>
#include <climits>

#define BS   32
#define NQ   300
#define NC   8192
#define NOBJ 64
#define NROW (BS * NQ)   // 9600
#define CPL  5           // cols per lane: lanes 0..59 own 5 contiguous cols
#define LPAD 65          // padded LDS row stride (words) for [j][t] cost tile
#define RPW  4           // rows per wave in the logz kernel

// ---------------------------------------------------------------------------
// helpers (f32 cross-lane: 1 readlane / 1 DPP per step)
// ---------------------------------------------------------------------------
__device__ __forceinline__ float bcast_f32(float v, int lane) {
    union { float f; int i; } c, r;
    c.f = v;
    r.i = __builtin_amdgcn_readlane(c.i, lane);
    return r.f;
}

template <int CTRL>
__device__ __forceinline__ float dpp_min_step_f32(float x) {
    union { float f; int i; } c, r;
    c.f = x;
    r.i = __builtin_amdgcn_update_dpp(c.i, c.i, CTRL, 0xF, 0xF, false);
    return fminf(x, r.f);
}

// full-wave64 min: result valid in lane 63 (validated rounds 3-11, absmax 0)
__device__ __forceinline__ float wave_min_f32(float x) {
    x = dpp_min_step_f32<0x111>(x);  // row_shr:1
    x = dpp_min_step_f32<0x112>(x);  // row_shr:2
    x = dpp_min_step_f32<0x114>(x);  // row_shr:4
    x = dpp_min_step_f32<0x118>(x);  // row_shr:8
    x = dpp_min_step_f32<0x142>(x);  // row_bcast:15
    x = dpp_min_step_f32<0x143>(x);  // row_bcast:31
    return x;
}

// compile-time-index select over a 5-reg int array (stays in VGPRs)
__device__ __forceinline__ int sel5(const int (&a)[CPL], int k) {
    int r = a[0];
    r = (k == 1) ? a[1] : r;
    r = (k == 2) ? a[2] : r;
    r = (k == 3) ? a[3] : r;
    r = (k == 4) ? a[4] : r;
    return r;
}

// ---------------------------------------------------------------------------
// Kernel 1: logZ + cost rows, 4 rows per wave with interleaved accumulation.
// The per-row reduce tails are deferred past the fused 4-stream k-loop, so
// the load pipeline never drains mid-block (was: 1 row/wave -> ~150cy bubble
// every 32KB). Label compaction is in-register via ds_permute push (no LDS,
// no block sync). Gathers still issue before the stream (round-8 pattern).
// ---------------------------------------------------------------------------
__global__ __launch_bounds__(256) void logz_cost_kernel(const float* __restrict__ x,
                                                        const int* __restrict__ labels,
                                                        float* __restrict__ logZ,
                                                        float* __restrict__ costQ,
                                                        float* __restrict__ out) {
    int wave    = threadIdx.x >> 6;
    int lane    = threadIdx.x & 63;
    int rowbase = blockIdx.x * (4 * RPW) + wave * RPW;   // 600 blocks * 16 = 9600

    if (blockIdx.x == 0 && threadIdx.x == 0) out[0] = 0.f;

    // per-row label compaction (rows may span 2 batches) + gather-first
    int   nb_r[RPW];
    float xv_r[RPW];
    #pragma unroll
    for (int r = 0; r < RPW; ++r) {
        int row = rowbase + r;
        int b   = row / NQ;
        int lab = labels[b * NOBJ + lane];               // 256B, L2-hot
        unsigned long long mask = __ballot(lab != 0);
        nb_r[r] = __popcll(mask);
        int pos = __popcll(mask & ((1ull << lane) - 1ull));
        // push-compact: lane 'pos' receives lab of this lane
        int cls = __builtin_amdgcn_ds_permute(pos << 2, lab);
        xv_r[r] = (lane < nb_r[r]) ? x[(size_t)row * NC + cls] : 0.f;
    }

    // fused 4-stream accumulation: 4 x float4 per lane per iteration
    const float4* p0 = (const float4*)(x + (size_t)(rowbase + 0) * NC);
    const float4* p1 = (const float4*)(x + (size_t)(rowbase + 1) * NC);
    const float4* p2 = (const float4*)(x + (size_t)(rowbase + 2) * NC);
    const float4* p3 = (const float4*)(x + (size_t)(rowbase + 3) * NC);
    float a0 = 0.f, a1 = 0.f, a2 = 0.f, a3 = 0.f;
    float b0 = 0.f, b1 = 0.f, b2 = 0.f, b3 = 0.f;
    float c0 = 0.f, c1 = 0.f, c2 = 0.f, c3 = 0.f;
    float d0 = 0.f, d1 = 0.f, d2 = 0.f, d3 = 0.f;
    #pragma unroll 4
    for (int k = 0; k < NC / 4 / 64; ++k) {   // 32 iterations
        float4 v0 = p0[lane + k * 64];
        float4 v1 = p1[lane + k * 64];
        float4 v2 = p2[lane + k * 64];
        float4 v3 = p3[lane + k * 64];
        a0 += __expf(v0.x); a1 += __expf(v0.y); a2 += __expf(v0.z); a3 += __expf(v0.w);
        b0 += __expf(v1.x); b1 += __expf(v1.y); b2 += __expf(v1.z); b3 += __expf(v1.w);
        c0 += __expf(v2.x); c1 += __expf(v2.y); c2 += __expf(v2.z); c3 += __expf(v2.w);
        d0 += __expf(v3.x); d1 += __expf(v3.y); d2 += __expf(v3.z); d3 += __expf(v3.w);
    }
    float sums[RPW] = { (a0 + a1) + (a2 + a3), (b0 + b1) + (b2 + b3),
                        (c0 + c1) + (c2 + c3), (d0 + d1) + (d2 + d3) };

    // deferred reduce tails + stores
    #pragma unroll
    for (int r = 0; r < RPW; ++r) {
        int   row = rowbase + r;
        float s   = sums[r];
        for (int off = 32; off; off >>= 1)
            s += __shfl_xor(s, off);
        float lz = logf(s);
        if (lane == 0) logZ[row] = lz;
        float c = (lane < nb_r[r]) ? -__expf(xv_r[r] - lz) : 0.f;
        costQ[(size_t)row * NOBJ + lane] = c;      // coalesced 256B
    }
}

// ---------------------------------------------------------------------------
// Kernel 2: JV assignment with DOUBLE reduction (column then row) + greedy
// seeding, one block per batch; solver on wave 0.
// (unchanged from round 11; absmax 0 through rounds 5-11)
// ---------------------------------------------------------------------------
__global__ __launch_bounds__(256) void hungarian_kernel(const float* __restrict__ costQ,
                                                        const int* __restrict__ labels,
                                                        const float* __restrict__ x,
                                                        const float* __restrict__ logZ,
                                                        float* __restrict__ out) {
    int b    = blockIdx.x;
    int tid  = threadIdx.x;
    int lane = tid & 63;
    int wid  = tid >> 6;

    __shared__ float cst[NQ * LPAD];   // 300*65*4 = 78 KB, layout [j][t]
    __shared__ float v_sh[NQ];         // column-reduction duals
    __shared__ int   col_owner[NQ];    // greedy seeding scratch

    int lab = 0, n = 0;
    if (wid == 0) {
        lab = labels[b * NOBJ + lane];
        n   = __popcll(__ballot(lab != 0));
    }

    // stage costQ -> LDS transpose-pad with all 256 threads
    {
        const float4* src = (const float4*)(costQ + (size_t)b * NQ * NOBJ);
        #pragma unroll
        for (int t = 0; t < 19; ++t) {   // 19*256 >= 4800
            int idx = tid + t * 256;
            if (idx < NQ * NOBJ / 4) {
                float4 v = src[idx];
                int e  = 4 * idx;
                int j  = e >> 6;        // query index
                int t0 = e & 63;        // target index (multiple of 4)
                float* d = &cst[j * LPAD + t0];
                d[0] = v.x; d[1] = v.y; d[2] = v.z; d[3] = v.w;
            }
        }
    }
    for (int j = tid; j < NQ; j += 256) col_owner[j] = INT_MAX;
    __syncthreads();

    // ---- column reduction with all 4 waves: v[j] = min_t cst[j][t] --------
    for (int j = tid; j < NQ; j += 256) {
        float mn = INFINITY;
        #pragma unroll 8
        for (int t = 0; t < NOBJ; ++t)
            mn = fminf(mn, cst[j * LPAD + t]);
        v_sh[j] = mn;
    }
    __syncthreads();
    if (wid != 0) return;               // solver is wave 0 only; no barriers below

    const int  jbase    = lane * CPL + 1;
    const bool haveCols = (lane < 60);

    // ---- row reduction on reduced costs: u[i] = min_j (c[i][j] - v[j]) ----
    float rmin = INFINITY;
    int   rarg = 0;
    if (lane < n) {
        #pragma unroll 4
        for (int j = 0; j < NQ; ++j) {
            float red = cst[j * LPAD + lane] - v_sh[j];
            if (red < rmin) { rmin = red; rarg = j; }    // first-index on ties
        }
    }
    float u_val = (lane < n) ? rmin : 0.f;

    // ---- greedy seeding: lowest row wins each column (wave-local atomics) --
    if (lane < n) atomicMin(&col_owner[rarg], lane);
    bool won = (lane < n) && (col_owner[rarg] == lane);
    if ((lane < n) && !won) atomicCAS(&col_owner[rarg], lane, INT_MAX);

    float v_r[CPL], minv_r[CPL];
    int   p_r[CPL], way_r[CPL];
    #pragma unroll
    for (int k = 0; k < CPL; ++k) {
        way_r[k] = 0;
        v_r[k]   = haveCols ? v_sh[jbase - 1 + k] : 0.f;
        int own  = haveCols ? col_owner[jbase - 1 + k] : INT_MAX;
        p_r[k]   = (own != INT_MAX) ? own + 1 : 0;
    }

    unsigned long long todo = __ballot((lane < n) && !won);

    while (todo) {
        int i = (int)__ffsll(todo);        // row index (1-based)
        todo &= todo - 1;

        #pragma unroll
        for (int k = 0; k < CPL; ++k) minv_r[k] = INFINITY;
        int  usedbits = 0;
        bool inTree   = (lane == i - 1);   // virtual col 0: p[0]=i
        int  i0 = i, j0 = 0, jfin;
        float ui0 = bcast_f32(u_val, i - 1);

        while (true) {
            // 1. issue LDS loads ASAP (addresses depend only on i0)
            int cbase = i0 - 1;
            float ld[CPL];
            #pragma unroll
            for (int k = 0; k < CPL; ++k)
                ld[k] = cst[(jbase - 1 + k) * LPAD + cbase];

            // 2. scan: update minv, track per-lane (lv, kmin); k asc = first-j
            float lv = INFINITY;
            int   kmin = 0;
            if (haveCols) {
                #pragma unroll
                for (int k = 0; k < CPL; ++k) {
                    if (!((usedbits >> k) & 1)) {
                        float cur = ld[k] - ui0 - v_r[k];
                        if (cur < minv_r[k]) { minv_r[k] = cur; way_r[k] = j0; }
                        if (minv_r[k] < lv) { lv = minv_r[k]; kmin = k; }
                    }
                }
            }
            int pv_cand = sel5(p_r, kmin);      // own candidate, overlaps DPP
            int lj      = jbase + kmin;

            // 3. exact f32 min + owner (lowest lane == lowest j)
            float delta = bcast_f32(wave_min_f32(lv), 63);
            unsigned long long msk = __ballot(lv == delta);
            int owner = (int)__ffsll(msk) - 1;
            int j1    = __builtin_amdgcn_readlane(lj, owner);
            int i0n   = __builtin_amdgcn_readlane(pv_cand, owner);
            // 4. prefetch u[i0n] BEFORE delta update (i0n not in tree)
            float u_next = (i0n > 0) ? bcast_f32(u_val, i0n - 1) : 0.f;

            // 5. price updates
            if (inTree) u_val += delta;
            if (haveCols) {
                #pragma unroll
                for (int k = 0; k < CPL; ++k) {
                    if ((usedbits >> k) & 1) v_r[k]    -= delta;
                    else                     minv_r[k] -= delta;
                }
            }
            if (lane == owner) usedbits |= (1 << kmin);
            if (i0n == 0) { jfin = j1; break; }
            if (lane == i0n - 1) inTree = true;
            i0 = i0n; ui0 = u_next; j0 = j1;
        }

        // augment alternating path: p[jj] = p[way[jj]] (p[0] == i)
        int jj = jfin;
        while (jj) {
            int ow = (jj - 1) / CPL, kk = (jj - 1) % CPL;
            int jn = __builtin_amdgcn_readlane(sel5(way_r, kk), ow);
            int pn;
            if (jn == 0) {
                pn = i;
            } else {
                int ow2 = (jn - 1) / CPL, kk2 = (jn - 1) % CPL;
                pn = __builtin_amdgcn_readlane(sel5(p_r, kk2), ow2);
            }
            bool w = (lane == ow);
            p_r[0] = (w && kk == 0) ? pn : p_r[0];
            p_r[1] = (w && kk == 1) ? pn : p_r[1];
            p_r[2] = (w && kk == 2) ? pn : p_r[2];
            p_r[3] = (w && kk == 3) ? pn : p_r[3];
            p_r[4] = (w && kk == 4) ? pn : p_r[4];
            jj = jn;
        }
    }

    // fused loss: sum over this batch's 300 queries of (x[q,t]-logZ[q]),
    // then one atomic accumulate of the scaled contribution into out[0].
    double acc = 0.0;
    if (haveCols) {
        #pragma unroll
        for (int k = 0; k < CPL; ++k) {
            int q  = jbase - 1 + k;
            int pr = p_r[k];
            int t  = (pr > 0) ? pr - 1 : 0;
            int rg = b * NQ + q;
            float xv = x[(size_t)rg * NC + t];
            acc += (double)(xv - logZ[rg]);
        }
    }
    for (int off = 32; off; off >>= 1)
        acc += __shfl_xor(acc, off);
    if (lane == 0) atomicAdd(out, (float)(-acc / (double)NROW));
}

// ---------------------------------------------------------------------------
extern "C" void kernel_launch(void* const* d_in, const int* in_sizes, int n_in,
                              void* d_out, int out_size, void* d_ws, size_t ws_size,
                              hipStream_t stream) {
    const float* outputs = (const float*)d_in[0];
    const int*   labels  = (const int*)d_in[1];
    float*       out     = (float*)d_out;

    char* ws = (char*)d_ws;
    size_t off = 0;
    float* logZ  = (float*)(ws + off); off += (size_t)NROW * sizeof(float);
    float* costQ = (float*)(ws + off); off += (size_t)NROW * NOBJ * sizeof(float);

    logz_cost_kernel<<<NROW / (4 * RPW), 256, 0, stream>>>(outputs, labels, logZ, costQ, out);
    hungarian_kernel<<<BS, 256, 0, stream>>>(costQ, labels, outputs, logZ, out);
}

// Round 13
// 80.872 us; speedup vs baseline: 1.1457x; 1.1457x over previous
//
#include <hip/hip_runtime.h>
#include <hip/hip_bf16.h>
#include <cfloat>
#include <climits>

#define BS   32
#define NQ   300
#define NC   8192
#define NOBJ 64
#define NROW (BS * NQ)   // 9600
#define CPL  5           // cols per lane: lanes 0..59 own 5 contiguous cols
#define LPAD 65          // padded LDS row stride (words) for [j][t] cost tile

// ---------------------------------------------------------------------------
// helpers (f32 cross-lane: 1 readlane / 1 DPP per step)
// ---------------------------------------------------------------------------
__device__ __forceinline__ float bcast_f32(float v, int lane) {
    union { float f; int i; } c, r;
    c.f = v;
    r.i = __builtin_amdgcn_readlane(c.i, lane);
    return r.f;
}

template <int CTRL>
__device__ __forceinline__ float dpp_min_step_f32(float x) {
    union { float f; int i; } c, r;
    c.f = x;
    r.i = __builtin_amdgcn_update_dpp(c.i, c.i, CTRL, 0xF, 0xF, false);
    return fminf(x, r.f);
}

// full-wave64 min: result valid in lane 63 (validated rounds 3-11, absmax 0)
__device__ __forceinline__ float wave_min_f32(float x) {
    x = dpp_min_step_f32<0x111>(x);  // row_shr:1
    x = dpp_min_step_f32<0x112>(x);  // row_shr:2
    x = dpp_min_step_f32<0x114>(x);  // row_shr:4
    x = dpp_min_step_f32<0x118>(x);  // row_shr:8
    x = dpp_min_step_f32<0x142>(x);  // row_bcast:15
    x = dpp_min_step_f32<0x143>(x);  // row_bcast:31
    return x;
}

// compile-time-index select over a 5-reg int array (stays in VGPRs)
__device__ __forceinline__ int sel5(const int (&a)[CPL], int k) {
    int r = a[0];
    r = (k == 1) ? a[1] : r;
    r = (k == 2) ? a[2] : r;
    r = (k == 3) ? a[3] : r;
    r = (k == 4) ? a[4] : r;
    return r;
}

// ---------------------------------------------------------------------------
// Kernel 1 (fused): logZ per row + cost row costQ[row][t] = -exp(x - logZ).
// One row per wave, 2400 blocks (9600 waves -> 32-waves/CU occupancy cap;
// round-12 lesson: TLP, not per-wave ILP, is what saturates the stream).
// Stream measured at ~91% of the float4-copy ceiling (6.29 TB/s, m13).
// ---------------------------------------------------------------------------
__global__ __launch_bounds__(256) void logz_cost_kernel(const float* __restrict__ x,
                                                        const int* __restrict__ labels,
                                                        float* __restrict__ logZ,
                                                        float* __restrict__ costQ,
                                                        float* __restrict__ out) {
    int wave = threadIdx.x >> 6;
    int lane = threadIdx.x & 63;
    int row  = blockIdx.x * 4 + wave;    // 2400 blocks * 4 = 9600 exactly
    int b    = row / NQ;

    if (blockIdx.x == 0 && threadIdx.x == 0) out[0] = 0.f;

    __shared__ int tgt_sh[4][NOBJ];
    int lab = labels[b * NOBJ + lane];
    unsigned long long mask = __ballot(lab != 0);
    int nb  = __popcll(mask);
    int pos = __popcll(mask & ((1ull << lane) - 1ull));
    if (lab != 0) tgt_sh[wave][pos] = lab;   // own wave's slice; lgkm-ordered

    float xv_g = 0.f;
    if (lane < nb) {
        int cls = tgt_sh[wave][lane];
        xv_g = x[(size_t)row * NC + cls];
    }

    const float4* p = (const float4*)(x + (size_t)row * NC);
    float s0 = 0.f, s1 = 0.f, s2 = 0.f, s3 = 0.f;
    #pragma unroll 8
    for (int k = 0; k < NC / 4 / 64; ++k) {   // 32 float4 per lane
        float4 v = p[lane + k * 64];
        s0 += __expf(v.x);
        s1 += __expf(v.y);
        s2 += __expf(v.z);
        s3 += __expf(v.w);
    }
    float s = (s0 + s1) + (s2 + s3);
    for (int off = 32; off; off >>= 1)
        s += __shfl_xor(s, off);
    float lz = logf(s);
    if (lane == 0) logZ[row] = lz;

    float c = (lane < nb) ? -__expf(xv_g - lz) : 0.f;
    costQ[(size_t)row * NOBJ + lane] = c;      // coalesced
}

// ---------------------------------------------------------------------------
// Kernel 2: JV assignment with DOUBLE reduction (column then row) + greedy
// seeding, one block per batch; solver on wave 0.
//   v[j] = min_i c[i][j]           (free columns get tight edges too ->
//   u[i] = min_j (c[i][j] - v[j])   Dijkstra trees shrink from ~45 to ~10)
// Greedy-seeded matches are tight (row argmin has reduced cost 0) ->
// complementary slackness holds -> exact optimum -> same unique assignment.
// Search/augment machinery identical to rounds 5-11 (f32 duals, absmax 0).
// ---------------------------------------------------------------------------
__global__ __launch_bounds__(256) void hungarian_kernel(const float* __restrict__ costQ,
                                                        const int* __restrict__ labels,
                                                        const float* __restrict__ x,
                                                        const float* __restrict__ logZ,
                                                        float* __restrict__ out) {
    int b    = blockIdx.x;
    int tid  = threadIdx.x;
    int lane = tid & 63;
    int wid  = tid >> 6;

    __shared__ float cst[NQ * LPAD];   // 300*65*4 = 78 KB, layout [j][t]
    __shared__ float v_sh[NQ];         // column-reduction duals
    __shared__ int   col_owner[NQ];    // greedy seeding scratch

    int lab = 0, n = 0;
    if (wid == 0) {
        lab = labels[b * NOBJ + lane];
        n   = __popcll(__ballot(lab != 0));
    }

    // stage costQ -> LDS transpose-pad with all 256 threads
    {
        const float4* src = (const float4*)(costQ + (size_t)b * NQ * NOBJ);
        #pragma unroll
        for (int t = 0; t < 19; ++t) {   // 19*256 >= 4800
            int idx = tid + t * 256;
            if (idx < NQ * NOBJ / 4) {
                float4 v = src[idx];
                int e  = 4 * idx;
                int j  = e >> 6;        // query index
                int t0 = e & 63;        // target index (multiple of 4)
                float* d = &cst[j * LPAD + t0];
                d[0] = v.x; d[1] = v.y; d[2] = v.z; d[3] = v.w;
            }
        }
    }
    for (int j = tid; j < NQ; j += 256) col_owner[j] = INT_MAX;
    __syncthreads();

    // ---- column reduction with all 4 waves: v[j] = min_t cst[j][t] --------
    for (int j = tid; j < NQ; j += 256) {
        float mn = INFINITY;
        #pragma unroll 8
        for (int t = 0; t < NOBJ; ++t)
            mn = fminf(mn, cst[j * LPAD + t]);
        v_sh[j] = mn;
    }
    __syncthreads();
    if (wid != 0) return;               // solver is wave 0 only; no barriers below

    const int  jbase    = lane * CPL + 1;
    const bool haveCols = (lane < 60);

    // ---- row reduction on reduced costs: u[i] = min_j (c[i][j] - v[j]) ----
    float rmin = INFINITY;
    int   rarg = 0;
    if (lane < n) {
        #pragma unroll 4
        for (int j = 0; j < NQ; ++j) {
            float red = cst[j * LPAD + lane] - v_sh[j];
            if (red < rmin) { rmin = red; rarg = j; }    // first-index on ties
        }
    }
    float u_val = (lane < n) ? rmin : 0.f;

    // ---- greedy seeding: lowest row wins each column (wave-local atomics) --
    if (lane < n) atomicMin(&col_owner[rarg], lane);
    bool won = (lane < n) && (col_owner[rarg] == lane);
    if ((lane < n) && !won) atomicCAS(&col_owner[rarg], lane, INT_MAX);

    float v_r[CPL], minv_r[CPL];
    int   p_r[CPL], way_r[CPL];
    #pragma unroll
    for (int k = 0; k < CPL; ++k) {
        way_r[k] = 0;
        v_r[k]   = haveCols ? v_sh[jbase - 1 + k] : 0.f;
        int own  = haveCols ? col_owner[jbase - 1 + k] : INT_MAX;
        p_r[k]   = (own != INT_MAX) ? own + 1 : 0;
    }

    unsigned long long todo = __ballot((lane < n) && !won);

    while (todo) {
        int i = (int)__ffsll(todo);        // row index (1-based)
        todo &= todo - 1;

        #pragma unroll
        for (int k = 0; k < CPL; ++k) minv_r[k] = INFINITY;
        int  usedbits = 0;
        bool inTree   = (lane == i - 1);   // virtual col 0: p[0]=i
        int  i0 = i, j0 = 0, jfin;
        float ui0 = bcast_f32(u_val, i - 1);

        while (true) {
            // 1. issue LDS loads ASAP (addresses depend only on i0)
            int cbase = i0 - 1;
            float ld[CPL];
            #pragma unroll
            for (int k = 0; k < CPL; ++k)
                ld[k] = cst[(jbase - 1 + k) * LPAD + cbase];

            // 2. scan: update minv, track per-lane (lv, kmin); k asc = first-j
            float lv = INFINITY;
            int   kmin = 0;
            if (haveCols) {
                #pragma unroll
                for (int k = 0; k < CPL; ++k) {
                    if (!((usedbits >> k) & 1)) {
                        float cur = ld[k] - ui0 - v_r[k];
                        if (cur < minv_r[k]) { minv_r[k] = cur; way_r[k] = j0; }
                        if (minv_r[k] < lv) { lv = minv_r[k]; kmin = k; }
                    }
                }
            }
            int pv_cand = sel5(p_r, kmin);      // own candidate, overlaps DPP
            int lj      = jbase + kmin;

            // 3. exact f32 min + owner (lowest lane == lowest j)
            float delta = bcast_f32(wave_min_f32(lv), 63);
            unsigned long long msk = __ballot(lv == delta);
            int owner = (int)__ffsll(msk) - 1;
            int j1    = __builtin_amdgcn_readlane(lj, owner);
            int i0n   = __builtin_amdgcn_readlane(pv_cand, owner);
            // 4. prefetch u[i0n] BEFORE delta update (i0n not in tree)
            float u_next = (i0n > 0) ? bcast_f32(u_val, i0n - 1) : 0.f;

            // 5. price updates
            if (inTree) u_val += delta;
            if (haveCols) {
                #pragma unroll
                for (int k = 0; k < CPL; ++k) {
                    if ((usedbits >> k) & 1) v_r[k]    -= delta;
                    else                     minv_r[k] -= delta;
                }
            }
            if (lane == owner) usedbits |= (1 << kmin);
            if (i0n == 0) { jfin = j1; break; }
            if (lane == i0n - 1) inTree = true;
            i0 = i0n; ui0 = u_next; j0 = j1;
        }

        // augment alternating path: p[jj] = p[way[jj]] (p[0] == i)
        int jj = jfin;
        while (jj) {
            int ow = (jj - 1) / CPL, kk = (jj - 1) % CPL;
            int jn = __builtin_amdgcn_readlane(sel5(way_r, kk), ow);
            int pn;
            if (jn == 0) {
                pn = i;
            } else {
                int ow2 = (jn - 1) / CPL, kk2 = (jn - 1) % CPL;
                pn = __builtin_amdgcn_readlane(sel5(p_r, kk2), ow2);
            }
            bool w = (lane == ow);
            p_r[0] = (w && kk == 0) ? pn : p_r[0];
            p_r[1] = (w && kk == 1) ? pn : p_r[1];
            p_r[2] = (w && kk == 2) ? pn : p_r[2];
            p_r[3] = (w && kk == 3) ? pn : p_r[3];
            p_r[4] = (w && kk == 4) ? pn : p_r[4];
            jj = jn;
        }
    }

    // fused loss: sum over this batch's 300 queries of (x[q,t]-logZ[q]),
    // then one atomic accumulate of the scaled contribution into out[0].
    double acc = 0.0;
    if (haveCols) {
        #pragma unroll
        for (int k = 0; k < CPL; ++k) {
            int q  = jbase - 1 + k;
            int pr = p_r[k];
            int t  = (pr > 0) ? pr - 1 : 0;
            int rg = b * NQ + q;
            float xv = x[(size_t)rg * NC + t];
            acc += (double)(xv - logZ[rg]);
        }
    }
    for (int off = 32; off; off >>= 1)
        acc += __shfl_xor(acc, off);
    if (lane == 0) atomicAdd(out, (float)(-acc / (double)NROW));
}

// ---------------------------------------------------------------------------
extern "C" void kernel_launch(void* const* d_in, const int* in_sizes, int n_in,
                              void* d_out, int out_size, void* d_ws, size_t ws_size,
                              hipStream_t stream) {
    const float* outputs = (const float*)d_in[0];
    const int*   labels  = (const int*)d_in[1];
    float*       out     = (float*)d_out;

    char* ws = (char*)d_ws;
    size_t off = 0;
    float* logZ  = (float*)(ws + off); off += (size_t)NROW * sizeof(float);
    float* costQ = (float*)(ws + off); off += (size_t)NROW * NOBJ * sizeof(float);

    logz_cost_kernel<<<NROW / 4, 256, 0, stream>>>(outputs, labels, logZ, costQ, out);
    hungarian_kernel<<<BS, 256, 0, stream>>>(costQ, labels, outputs, logZ, out);
}